// Round 4
// baseline (680.278 us; speedup 1.0000x reference)
//
#include <hip/hip_runtime.h>
#include <stdint.h>

#define NB 8
#define NT 1024
#define ND 768
#define NV 768
#define NL 13
#define MTOK (NB*NT)          // 8192
#define MROWS (MTOK*NL)       // 106496

typedef __attribute__((ext_vector_type(8))) short short8;
typedef __attribute__((ext_vector_type(4))) float f32x4;

__device__ __forceinline__ unsigned short f2bf(float f) {
    union { float f; unsigned u; } v; v.f = f;
    unsigned r = v.u + 0x7FFFu + ((v.u >> 16) & 1u);
    return (unsigned short)(r >> 16);
}
__device__ __forceinline__ float bf2f(unsigned short u) {
    union { unsigned u; float f; } v; v.u = ((unsigned)u) << 16;
    return v.f;
}
__device__ __forceinline__ unsigned cvtpk(float lo, float hi) {
    unsigned r;
    asm("v_cvt_pk_bf16_f32 %0, %1, %2" : "=v"(r) : "v"(lo), "v"(hi));
    return r;
}
__device__ __forceinline__ void gload16(const void* g, void* l) {
    __builtin_amdgcn_global_load_lds(
        (const __attribute__((address_space(1))) unsigned int*)g,
        (__attribute__((address_space(3))) unsigned int*)l, 16, 0, 0);
}

// ---------------------------------------------------------------------------
// fp32 -> bf16 bulk convert (weights only)
// ---------------------------------------------------------------------------
__global__ __launch_bounds__(256) void conv_f32_bf16(
    const float* __restrict__ s, unsigned short* __restrict__ d, long n)
{
    long i = ((long)blockIdx.x * 256 + threadIdx.x) * 8;
    long st = (long)gridDim.x * 2048;
    for (; i < n; i += st) {
        float4 a = *(const float4*)(s + i);
        float4 b = *(const float4*)(s + i + 4);
        ushort4 u0, u1;
        u0.x = f2bf(a.x); u0.y = f2bf(a.y); u0.z = f2bf(a.z); u0.w = f2bf(a.w);
        u1.x = f2bf(b.x); u1.y = f2bf(b.y); u1.z = f2bf(b.z); u1.w = f2bf(b.w);
        *(ushort4*)(d + i)     = u0;
        *(ushort4*)(d + i + 4) = u1;
    }
}

// ---------------------------------------------------------------------------
// GEMM1: C(bf16) = A(fp32) * B(bf16)^T + bias.
// 1-D grid 4992, XCD-grouped: xcd=bid&7 owns 104 (layer,m)-groups of 6 n-blocks.
// kg-major LDS (chunk-major) via permuted global_load_lds sources -> conflict-
// free ds_reads.  128x128 tile, BK=32, double-buffered.
// ---------------------------------------------------------------------------
__global__ __launch_bounds__(256) void gemm_f32a(
    const float* __restrict__ A, const unsigned short* __restrict__ B,
    const float* __restrict__ biasBase, unsigned short* __restrict__ C,
    int K, long aLS, long bLS, int biasLS, long cLayerOff, long cRowStride)
{
    __shared__ __align__(16) float          lsA[2][4096];  // [8 chunk][128 row][4 f32]
    __shared__ __align__(16) unsigned short lsB[2][4096];  // [4 chunk][128 row][8 bf16]

    const int bid = blockIdx.x;
    const int xcd = bid & 7, slot = bid >> 3;        // 624 slots per XCD
    const int grp = xcd * 104 + slot / 6;            // z-major group id
    const int nx  = slot % 6;
    const int l   = grp >> 6;                        // layer 0..12
    const long m0 = (long)(grp & 63) * 128;
    const long n0 = (long)nx * 128;

    const int t = threadIdx.x, lane = t & 63, wave = t >> 6;
    const int rowL = t & 127, hi = t >> 7;

    const float* Ab = A + (size_t)l * aLS;
    const unsigned short* Bb = B + (size_t)l * bLS;
    const float* bias = biasBase + (size_t)l * biasLS;

    // kg-major staging sources: dest chunk cd=i*256+t -> (g=cd>>7, row=cd&127)
    const float* aSrc = Ab + (m0 + rowL) * (size_t)K + hi * 4;
    const unsigned short* bSrc = Bb + (n0 + rowL) * (size_t)K + hi * 8;

    const int wm = (wave >> 1) * 64;
    const int wn = (wave & 1) * 64;
    const int lr = lane & 15;
    const int g4 = lane >> 4;

    f32x4 acc[4][4];
#pragma unroll
    for (int i = 0; i < 4; i++)
#pragma unroll
        for (int j = 0; j < 4; j++) acc[i][j] = (f32x4){0.f, 0.f, 0.f, 0.f};

    auto STAGE = [&](int buf, int k0) {
        char* la = (char*)lsA[buf];
        char* lb = (char*)lsB[buf];
#pragma unroll
        for (int i = 0; i < 4; i++)
            gload16(aSrc + k0 + i * 8, la + i * 4096 + t * 16);
#pragma unroll
        for (int i = 0; i < 2; i++)
            gload16(bSrc + k0 + i * 16, lb + i * 4096 + t * 16);
    };
    auto COMP = [&](int buf) {
        short8 af[4], bv[4];
        const float* pa = lsA[buf];
        const unsigned short* pb = lsB[buf];
#pragma unroll
        for (int mi = 0; mi < 4; mi++) {
            int row = wm + mi * 16 + lr;
            float4 x0 = *(const float4*)&pa[(2 * g4 * 128 + row) * 4];
            float4 x1 = *(const float4*)&pa[((2 * g4 + 1) * 128 + row) * 4];
            union { short8 s; unsigned u[4]; } ua;
            ua.u[0] = cvtpk(x0.x, x0.y); ua.u[1] = cvtpk(x0.z, x0.w);
            ua.u[2] = cvtpk(x1.x, x1.y); ua.u[3] = cvtpk(x1.z, x1.w);
            af[mi] = ua.s;
        }
#pragma unroll
        for (int ni = 0; ni < 4; ni++)
            bv[ni] = *(const short8*)&pb[(g4 * 128 + wn + ni * 16 + lr) * 8];
#pragma unroll
        for (int mi = 0; mi < 4; mi++)
#pragma unroll
            for (int ni = 0; ni < 4; ni++)
                acc[mi][ni] = __builtin_amdgcn_mfma_f32_16x16x32_bf16(
                    af[mi], bv[ni], acc[mi][ni], 0, 0, 0);
    };

    STAGE(0, 0);
    __syncthreads();
    int cur = 0;
    const int nst = K >> 5;
    for (int ks = 1; ks < nst; ks++) {
        STAGE(cur ^ 1, ks * 32);
        COMP(cur);
        __syncthreads();
        cur ^= 1;
    }
    COMP(cur);

#pragma unroll
    for (int ni = 0; ni < 4; ni++) {
        long col = n0 + wn + ni * 16 + lr;
        float bvs = bias[col];
#pragma unroll
        for (int mi = 0; mi < 4; mi++) {
#pragma unroll
            for (int r = 0; r < 4; r++) {
                long grow = m0 + wm + mi * 16 + (lane >> 4) * 4 + r;
                size_t coff = (size_t)grow * cRowStride + (size_t)l * cLayerOff + col;
                C[coff] = f2bf(acc[mi][ni][r] + bvs);
            }
        }
    }
}

// ---------------------------------------------------------------------------
// GEMM2: C(f32) = A(bf16) * B(bf16)^T + bias.  Same swizzle/layout scheme.
// grid = 384 (8 XCD x 8 groups x 6 n-blocks).
// ---------------------------------------------------------------------------
__global__ __launch_bounds__(256) void gemm_bf16_nt(
    const unsigned short* __restrict__ A, const unsigned short* __restrict__ B,
    const float* __restrict__ bias, float* __restrict__ C,
    int K, long cRowStride)
{
    __shared__ __align__(16) unsigned short lsA[2][4096];
    __shared__ __align__(16) unsigned short lsB[2][4096];

    const int bid = blockIdx.x;
    const int xcd = bid & 7, slot = bid >> 3;        // 48 slots per XCD
    const int grp = xcd * 8 + slot / 6;              // 0..63
    const int nx  = slot % 6;
    const long m0 = (long)grp * 128;
    const long n0 = (long)nx * 128;

    const int t = threadIdx.x, lane = t & 63, wave = t >> 6;
    const int rowL = t & 127, hi = t >> 7;

    const unsigned short* aSrc = A + (m0 + rowL) * (size_t)K + hi * 8;
    const unsigned short* bSrc = B + (n0 + rowL) * (size_t)K + hi * 8;

    const int wm = (wave >> 1) * 64;
    const int wn = (wave & 1) * 64;
    const int lr = lane & 15;
    const int g4 = lane >> 4;

    f32x4 acc[4][4];
#pragma unroll
    for (int i = 0; i < 4; i++)
#pragma unroll
        for (int j = 0; j < 4; j++) acc[i][j] = (f32x4){0.f, 0.f, 0.f, 0.f};

    auto STAGE = [&](int buf, int k0) {
        char* la = (char*)lsA[buf];
        char* lb = (char*)lsB[buf];
#pragma unroll
        for (int i = 0; i < 2; i++) {
            gload16(aSrc + k0 + i * 16, la + i * 4096 + t * 16);
            gload16(bSrc + k0 + i * 16, lb + i * 4096 + t * 16);
        }
    };
    auto COMP = [&](int buf) {
        short8 af[4], bv[4];
        const unsigned short* pa = lsA[buf];
        const unsigned short* pb = lsB[buf];
#pragma unroll
        for (int mi = 0; mi < 4; mi++)
            af[mi] = *(const short8*)&pa[(g4 * 128 + wm + mi * 16 + lr) * 8];
#pragma unroll
        for (int ni = 0; ni < 4; ni++)
            bv[ni] = *(const short8*)&pb[(g4 * 128 + wn + ni * 16 + lr) * 8];
#pragma unroll
        for (int mi = 0; mi < 4; mi++)
#pragma unroll
            for (int ni = 0; ni < 4; ni++)
                acc[mi][ni] = __builtin_amdgcn_mfma_f32_16x16x32_bf16(
                    af[mi], bv[ni], acc[mi][ni], 0, 0, 0);
    };

    STAGE(0, 0);
    __syncthreads();
    int cur = 0;
    const int nst = K >> 5;
    for (int ks = 1; ks < nst; ks++) {
        STAGE(cur ^ 1, ks * 32);
        COMP(cur);
        __syncthreads();
        cur ^= 1;
    }
    COMP(cur);

#pragma unroll
    for (int ni = 0; ni < 4; ni++) {
        long col = n0 + wn + ni * 16 + lr;
        float bvs = bias[col];
#pragma unroll
        for (int mi = 0; mi < 4; mi++) {
#pragma unroll
            for (int r = 0; r < 4; r++) {
                long grow = m0 + wm + mi * 16 + (lane >> 4) * 4 + r;
                C[(size_t)grow * cRowStride + col] = acc[mi][ni][r] + bvs;
            }
        }
    }
}

// ---------------------------------------------------------------------------
// Fold kvln gamma into k_w; compute s_k = sum(kw*g), c_k = kw.b + k_bias.
// ---------------------------------------------------------------------------
__global__ __launch_bounds__(256) void wtrans(
    const float* __restrict__ kw, const float* __restrict__ kvg,
    const float* __restrict__ kvb, const float* __restrict__ kbias,
    float* __restrict__ kwp, float* __restrict__ skv, float* __restrict__ ckv)
{
    __shared__ float red[8];
    const int q = blockIdx.x, t = threadIdx.x;
    const int lane = t & 63, wave = t >> 6;
    float s = 0.f, c = 0.f;
    for (int v = t; v < 768; v += 256) {
        float w = kw[q * 768 + v];
        float wp = w * kvg[v];
        kwp[q * 768 + v] = wp;
        s += wp;
        c += w * kvb[v];
    }
#pragma unroll
    for (int off = 1; off < 64; off <<= 1) {
        s += __shfl_xor(s, off);
        c += __shfl_xor(c, off);
    }
    if (lane == 0) { red[wave] = s; red[4 + wave] = c; }
    __syncthreads();
    if (t == 0) {
        skv[q] = red[0] + red[1] + red[2] + red[3];
        ckv[q] = red[4] + red[5] + red[6] + red[7] + kbias[q];
    }
}

// ---------------------------------------------------------------------------
// LayerNorm rows of 768 (fp32 src) -> bf16.  Q side only.
// ---------------------------------------------------------------------------
__global__ __launch_bounds__(256) void ln_rows_f32(
    const float* __restrict__ src, unsigned short* __restrict__ dst,
    const float* __restrict__ gam, const float* __restrict__ bet)
{
    const int lane = threadIdx.x & 63;
    const int wave = threadIdx.x >> 6;
    const size_t row = (size_t)blockIdx.x * 4 + wave;

    float x[3][4];
    float s = 0.f, sq = 0.f;
#pragma unroll
    for (int i = 0; i < 3; i++) {
        int v = i * 256 + lane * 4;
        float4 f = *(const float4*)(src + row * 768 + v);
        x[i][0] = f.x; x[i][1] = f.y; x[i][2] = f.z; x[i][3] = f.w;
#pragma unroll
        for (int e = 0; e < 4; e++) { s += x[i][e]; sq += x[i][e] * x[i][e]; }
    }
#pragma unroll
    for (int off = 1; off < 64; off <<= 1) {
        s  += __shfl_xor(s, off);
        sq += __shfl_xor(sq, off);
    }
    float mean = s * (1.f / 768.f);
    float var  = sq * (1.f / 768.f) - mean * mean;
    float rs   = rsqrtf(var + 1e-5f);
#pragma unroll
    for (int i = 0; i < 3; i++) {
        int v = i * 256 + lane * 4;
        float4 gg = *(const float4*)(gam + v);
        float4 bb = *(const float4*)(bet + v);
        ushort4 o;
        o.x = f2bf((x[i][0] - mean) * rs * gg.x + bb.x);
        o.y = f2bf((x[i][1] - mean) * rs * gg.y + bb.y);
        o.z = f2bf((x[i][2] - mean) * rs * gg.z + bb.z);
        o.w = f2bf((x[i][3] - mean) * rs * gg.w + bb.w);
        *(ushort4*)(dst + row * 768 + v) = o;
    }
}

// ---------------------------------------------------------------------------
// proj32: out[M][32] = A[M][768](bf16) @ W[32][768](f32)^T + bias (plain).
// ---------------------------------------------------------------------------
__global__ __launch_bounds__(256) void proj32(
    const unsigned short* __restrict__ A, const float* __restrict__ W,
    const float* __restrict__ bias, unsigned short* __restrict__ out)
{
    __shared__ __align__(16) unsigned short lsW[32 * 776];
    __shared__ __align__(16) unsigned short lsA[128 * 40];
    const int t = threadIdx.x;

#pragma unroll
    for (int i = 0; i < 24; i++) {
        int fi = t + i * 256;
        int row = fi / 192;
        int c4  = fi % 192;
        float4 f = *(const float4*)(W + row * 768 + c4 * 4);
        ushort4 u;
        u.x = f2bf(f.x); u.y = f2bf(f.y); u.z = f2bf(f.z); u.w = f2bf(f.w);
        *(ushort4*)&lsW[row * 776 + c4 * 4] = u;
    }

    const size_t m0 = (size_t)blockIdx.x * 128;
    const int lane = t & 63, wave = t >> 6;
    const int wm = wave * 32;
    const int lr = lane & 15, kg = (lane >> 4) * 8;
    const int row_s = t >> 3, c4s = t & 7;

    f32x4 acc[2][2];
#pragma unroll
    for (int i = 0; i < 2; i++)
#pragma unroll
        for (int j = 0; j < 2; j++) acc[i][j] = (f32x4){0.f, 0.f, 0.f, 0.f};

    __syncthreads();

    for (int k0 = 0; k0 < 768; k0 += 32) {
#pragma unroll
        for (int i = 0; i < 4; i++) {
            int row = row_s + 32 * i;
            ushort4 v = *(const ushort4*)(A + (m0 + row) * 768 + k0 + c4s * 4);
            *(ushort4*)&lsA[row * 40 + c4s * 4] = v;
        }
        __syncthreads();
        short8 af[2], bw[2];
#pragma unroll
        for (int mi = 0; mi < 2; mi++)
            af[mi] = *(const short8*)&lsA[(wm + mi * 16 + lr) * 40 + kg];
#pragma unroll
        for (int ni = 0; ni < 2; ni++)
            bw[ni] = *(const short8*)&lsW[(ni * 16 + lr) * 776 + k0 + kg];
#pragma unroll
        for (int mi = 0; mi < 2; mi++)
#pragma unroll
            for (int ni = 0; ni < 2; ni++)
                acc[mi][ni] = __builtin_amdgcn_mfma_f32_16x16x32_bf16(
                    af[mi], bw[ni], acc[mi][ni], 0, 0, 0);
        __syncthreads();
    }

#pragma unroll
    for (int ni = 0; ni < 2; ni++) {
        int col = ni * 16 + lr;
        float bv = bias[col];
#pragma unroll
        for (int mi = 0; mi < 2; mi++) {
#pragma unroll
            for (int r = 0; r < 4; r++) {
                size_t grow = m0 + wm + mi * 16 + (lane >> 4) * 4 + r;
                out[grow * 32 + col] = f2bf(acc[mi][ni][r] + bv);
            }
        }
    }
}

// ---------------------------------------------------------------------------
// proj32k_stats: k = rs*(dot(x_raw, kwp) - mean*s_k) + c_k, with row stats
// (mean, rsqrt(var+eps)) computed IN the K-loop (fuses old stats_rows pass).
// ---------------------------------------------------------------------------
__global__ __launch_bounds__(256) void proj32k_stats(
    const unsigned short* __restrict__ A, const float* __restrict__ W,
    const float* __restrict__ skv, const float* __restrict__ ckv,
    unsigned short* __restrict__ out, float2* __restrict__ st)
{
    __shared__ __align__(16) unsigned short lsW[32 * 776];
    __shared__ __align__(16) unsigned short lsA[128 * 40];
    __shared__ float2 lstat[128];
    const int t = threadIdx.x;

#pragma unroll
    for (int i = 0; i < 24; i++) {
        int fi = t + i * 256;
        int row = fi / 192;
        int c4  = fi % 192;
        float4 f = *(const float4*)(W + row * 768 + c4 * 4);
        ushort4 u;
        u.x = f2bf(f.x); u.y = f2bf(f.y); u.z = f2bf(f.z); u.w = f2bf(f.w);
        *(ushort4*)&lsW[row * 776 + c4 * 4] = u;
    }

    const size_t m0 = (size_t)blockIdx.x * 128;
    const int lane = t & 63, wave = t >> 6;
    const int wm = wave * 32;
    const int lr = lane & 15, kg = (lane >> 4) * 8;
    const int row_s = t >> 3, c4s = t & 7;

    f32x4 acc[2][2];
#pragma unroll
    for (int i = 0; i < 2; i++)
#pragma unroll
        for (int j = 0; j < 2; j++) acc[i][j] = (f32x4){0.f, 0.f, 0.f, 0.f};

    float s_[4] = {0.f, 0.f, 0.f, 0.f}, sq_[4] = {0.f, 0.f, 0.f, 0.f};

    __syncthreads();

    for (int k0 = 0; k0 < 768; k0 += 32) {
#pragma unroll
        for (int i = 0; i < 4; i++) {
            int row = row_s + 32 * i;
            ushort4 v = *(const ushort4*)(A + (m0 + row) * 768 + k0 + c4s * 4);
            *(ushort4*)&lsA[row * 40 + c4s * 4] = v;
            float x0 = bf2f(v.x), x1 = bf2f(v.y), x2 = bf2f(v.z), x3 = bf2f(v.w);
            s_[i]  += x0 + x1 + x2 + x3;
            sq_[i] += x0 * x0 + x1 * x1 + x2 * x2 + x3 * x3;
        }
        __syncthreads();
        short8 af[2], bw[2];
#pragma unroll
        for (int mi = 0; mi < 2; mi++)
            af[mi] = *(const short8*)&lsA[(wm + mi * 16 + lr) * 40 + kg];
#pragma unroll
        for (int ni = 0; ni < 2; ni++)
            bw[ni] = *(const short8*)&lsW[(ni * 16 + lr) * 776 + k0 + kg];
#pragma unroll
        for (int mi = 0; mi < 2; mi++)
#pragma unroll
            for (int ni = 0; ni < 2; ni++)
                acc[mi][ni] = __builtin_amdgcn_mfma_f32_16x16x32_bf16(
                    af[mi], bw[ni], acc[mi][ni], 0, 0, 0);
        __syncthreads();
    }

    // finish row stats: 8 threads (c4s=0..7) hold col-partials per row
#pragma unroll
    for (int i = 0; i < 4; i++) {
#pragma unroll
        for (int off = 1; off < 8; off <<= 1) {
            s_[i]  += __shfl_xor(s_[i], off);
            sq_[i] += __shfl_xor(sq_[i], off);
        }
    }
    if (c4s == 0) {
#pragma unroll
        for (int i = 0; i < 4; i++) {
            int row = row_s + 32 * i;
            float mean = s_[i] * (1.f / 768.f);
            float var  = sq_[i] * (1.f / 768.f) - mean * mean;
            float2 sv = make_float2(mean, rsqrtf(var + 1e-5f));
            lstat[row] = sv;
            st[m0 + row] = sv;
        }
    }
    __syncthreads();

#pragma unroll
    for (int ni = 0; ni < 2; ni++) {
        int col = ni * 16 + lr;
        float sk = skv[col], ck = ckv[col];
#pragma unroll
        for (int mi = 0; mi < 2; mi++) {
#pragma unroll
            for (int r = 0; r < 4; r++) {
                int lrow = wm + mi * 16 + (lane >> 4) * 4 + r;
                float2 s2 = lstat[lrow];
                out[(m0 + lrow) * 32 + col] =
                    f2bf(s2.y * (acc[mi][ni][r] - s2.x * sk) + ck);
            }
        }
    }
}

// ---------------------------------------------------------------------------
// Attention on RAW aligned values with LN folded in.  One wave per token.
// ---------------------------------------------------------------------------
__global__ __launch_bounds__(256) void attn2(
    const unsigned short* __restrict__ qb, const unsigned short* __restrict__ kb,
    const unsigned short* __restrict__ kv, const float2* __restrict__ st,
    const float* __restrict__ gv, const float* __restrict__ bvv,
    unsigned short* __restrict__ oh)
{
    __shared__ float lat[4][4][13];
    __shared__ float latc[4][4];
    const int t = threadIdx.x, lane = t & 63, wave = t >> 6;
    const size_t m = (size_t)blockIdx.x * 4 + wave;

    if (lane < 32) {
        int j = lane;
        float qv = bf2f(qb[m * 32 + j]);
        float p[13];
#pragma unroll
        for (int l = 0; l < 13; l++)
            p[l] = qv * bf2f(kb[(m * 13 + l) * 32 + j]);
#pragma unroll
        for (int off = 1; off < 8; off <<= 1)
#pragma unroll
            for (int l = 0; l < 13; l++) p[l] += __shfl_xor(p[l], off);

        const float sc = 0.17677669529663687f; // 1 / (sqrt(8) * 2)
        float mx = -1e30f;
#pragma unroll
        for (int l = 0; l < 13; l++) { p[l] *= sc; mx = fmaxf(mx, p[l]); }
        float se = 0.f;
#pragma unroll
        for (int l = 0; l < 13; l++) { p[l] = __expf(p[l] - mx); se += p[l]; }
        float inv = 1.f / se;
        if ((j & 7) == 0) {
            int h = j >> 3;
            float corr = 0.f;
#pragma unroll
            for (int l = 0; l < 13; l++) {
                float2 s_ = st[m * 13 + l];
                float wl = p[l] * inv * s_.y;
                lat[wave][h][l] = wl;
                corr += wl * s_.x;
            }
            latc[wave][h] = corr;
        }
    }
    __syncthreads();

    f32x4 g4v[3], b4[3];
#pragma unroll
    for (int i = 0; i < 3; i++) {
        g4v[i] = *(const f32x4*)(gv + i * 256 + lane * 4);
        b4[i] = *(const f32x4*)(bvv + i * 256 + lane * 4);
    }

    float acc[4][3][4];
#pragma unroll
    for (int h = 0; h < 4; h++)
#pragma unroll
        for (int i = 0; i < 3; i++)
#pragma unroll
            for (int e = 0; e < 4; e++) acc[h][i][e] = 0.f;

    for (int l = 0; l < 13; l++) {
        float al[4];
#pragma unroll
        for (int h = 0; h < 4; h++) al[h] = lat[wave][h][l];
#pragma unroll
        for (int i = 0; i < 3; i++) {
            ushort4 u = *(const ushort4*)(kv + (m * 13 + l) * 768 + i * 256 + lane * 4);
            float xv[4] = {bf2f(u.x), bf2f(u.y), bf2f(u.z), bf2f(u.w)};
#pragma unroll
            for (int h = 0; h < 4; h++)
#pragma unroll
                for (int e = 0; e < 4; e++) acc[h][i][e] += al[h] * xv[e];
        }
    }
#pragma unroll
    for (int h = 0; h < 4; h++) {
        float ch = latc[wave][h];
#pragma unroll
        for (int i = 0; i < 3; i++) {
            ushort4 o;
            o.x = f2bf(g4v[i][0] * (acc[h][i][0] - ch) + b4[i][0]);
            o.y = f2bf(g4v[i][1] * (acc[h][i][1] - ch) + b4[i][1]);
            o.z = f2bf(g4v[i][2] * (acc[h][i][2] - ch) + b4[i][2]);
            o.w = f2bf(g4v[i][3] * (acc[h][i][3] - ch) + b4[i][3]);
            *(ushort4*)(oh + m * 3072 + h * 768 + i * 256 + lane * 4) = o;
        }
    }
}

// ---------------------------------------------------------------------------
extern "C" void kernel_launch(void* const* d_in, const int* in_sizes, int n_in,
                              void* d_out, int out_size, void* d_ws, size_t ws_size,
                              hipStream_t stream) {
    const float* base  = (const float*)d_in[0];
    const float* reps  = (const float*)d_in[1];
    const float* aw    = (const float*)d_in[2];
    const float* ab    = (const float*)d_in[3];
    const float* qg    = (const float*)d_in[4];
    const float* qbeta = (const float*)d_in[5];
    const float* kvg   = (const float*)d_in[6];
    const float* kvb   = (const float*)d_in[7];
    const float* qw    = (const float*)d_in[8];
    const float* qbias = (const float*)d_in[9];
    const float* kw    = (const float*)d_in[10];
    const float* kbias = (const float*)d_in[11];
    const float* ow    = (const float*)d_in[12];
    const float* obias = (const float*)d_in[13];
    float* out = (float*)d_out;

    float2* stats = (float2*)d_ws;                              // [MROWS]
    float* kwp = (float*)(stats + MROWS);                       // [32][768]
    float* skv = kwp + 32 * 768;                                // [32]
    float* ckv = skv + 32;                                      // [32]
    unsigned short* aligned = (unsigned short*)(ckv + 32);      // [MROWS][768]
    unsigned short* UNION = aligned + (size_t)MROWS * 768;      // awb -> Qn -> oh
    unsigned short* kbuf = UNION + (size_t)MTOK * 3072;         // [MROWS][32]
    unsigned short* qbuf = kbuf + (size_t)MROWS * 32;           // [MTOK][32]
    unsigned short* owb  = qbuf + (size_t)MTOK * 32;            // [768][3072]

    unsigned short* awb = UNION;

    // 0. weight conversions + LN folding precompute
    {
        long n = (long)NL * 768 * 768;
        conv_f32_bf16<<<(int)(n / 8 / 256), 256, 0, stream>>>(aw, awb, n);
        long n2 = (long)768 * 3072;
        conv_f32_bf16<<<(int)(n2 / 8 / 256), 256, 0, stream>>>(ow, owb, n2);
        wtrans<<<32, 256, 0, stream>>>(kw, kvg, kvb, kbias, kwp, skv, ckv);
    }

    // 1. aligner GEMM (XCD-grouped 1-D grid: 8 * 104 * 6 = 4992)
    gemm_f32a<<<4992, 256, 0, stream>>>(
        reps, awb, ab, aligned,
        768, (long)MTOK * 768, (long)768 * 768, 768,
        768L, (long)NL * 768);

    // 2. k projection + fused row stats
    proj32k_stats<<<MROWS / 128, 256, 0, stream>>>(
        aligned, kwp, skv, ckv, kbuf, stats);

    // 3. q side: LN(base) -> Qn, then proj32 (awb dead, reuse UNION)
    unsigned short* Qn = UNION;
    ln_rows_f32<<<MTOK / 4, 256, 0, stream>>>(base, Qn, qg, qbeta);
    proj32<<<MTOK / 128, 256, 0, stream>>>(Qn, qw, qbias, qbuf);

    // 4. attention on raw aligned (Qn dead, reuse UNION for oh)
    unsigned short* oh = UNION;
    attn2<<<MTOK / 4, 256, 0, stream>>>(qbuf, kbuf, aligned, stats, kvg, kvb, oh);

    // 5. out = out_heads @ out_w^T + out_b (XCD-grouped: 8 * 8 * 6 = 384)
    gemm_bf16_nt<<<384, 256, 0, stream>>>(oh, owb, obias, out, 3072, 768L);
}

// Round 5
// 464.332 us; speedup vs baseline: 1.4651x; 1.4651x over previous
//
#include <hip/hip_runtime.h>
#include <stdint.h>

#define NB 8
#define NT 1024
#define ND 768
#define NV 768
#define NL 13
#define MTOK (NB*NT)          // 8192
#define MROWS (MTOK*NL)       // 106496

typedef __attribute__((ext_vector_type(8))) short short8;
typedef __attribute__((ext_vector_type(4))) float f32x4;

__device__ __forceinline__ unsigned short f2bf(float f) {
    union { float f; unsigned u; } v; v.f = f;
    unsigned r = v.u + 0x7FFFu + ((v.u >> 16) & 1u);
    return (unsigned short)(r >> 16);
}
__device__ __forceinline__ float bf2f(unsigned short u) {
    union { unsigned u; float f; } v; v.u = ((unsigned)u) << 16;
    return v.f;
}
__device__ __forceinline__ unsigned cvtpk(float lo, float hi) {
    unsigned r;
    asm("v_cvt_pk_bf16_f32 %0, %1, %2" : "=v"(r) : "v"(lo), "v"(hi));
    return r;
}
__device__ __forceinline__ void gload16(const void* g, void* l) {
    __builtin_amdgcn_global_load_lds(
        (const __attribute__((address_space(1))) unsigned int*)g,
        (__attribute__((address_space(3))) unsigned int*)l, 16, 0, 0);
}

// ---------------------------------------------------------------------------
// fp32 -> bf16 bulk convert (weights only)
// ---------------------------------------------------------------------------
__global__ __launch_bounds__(256) void conv_f32_bf16(
    const float* __restrict__ s, unsigned short* __restrict__ d, long n)
{
    long i = ((long)blockIdx.x * 256 + threadIdx.x) * 8;
    long st = (long)gridDim.x * 2048;
    for (; i < n; i += st) {
        float4 a = *(const float4*)(s + i);
        float4 b = *(const float4*)(s + i + 4);
        ushort4 u0, u1;
        u0.x = f2bf(a.x); u0.y = f2bf(a.y); u0.z = f2bf(a.z); u0.w = f2bf(a.w);
        u1.x = f2bf(b.x); u1.y = f2bf(b.y); u1.z = f2bf(b.z); u1.w = f2bf(b.w);
        *(ushort4*)(d + i)     = u0;
        *(ushort4*)(d + i + 4) = u1;
    }
}

// ---------------------------------------------------------------------------
// GEMM1: C(bf16) = A(fp32) * B(bf16)^T + bias.
// XCD-grouped 1-D grid (8 XCD x 104 groups x 6 n-blocks = 4992).
// Coalesced linear-dest staging; source-chunk XOR swizzle (involution) for
// conflict-free LDS reads.  128x128 tile, BK=32, double-buffered.
// ---------------------------------------------------------------------------
__global__ __launch_bounds__(256) void gemm_f32a(
    const float* __restrict__ A, const unsigned short* __restrict__ B,
    const float* __restrict__ biasBase, unsigned short* __restrict__ C,
    int K, long aLS, long bLS, int biasLS, long cLayerOff, long cRowStride)
{
    __shared__ __align__(16) float          lsA[2][4096];  // [128 row][32 f32], row-major
    __shared__ __align__(16) unsigned short lsB[2][4096];  // [128 row][32 bf16]

    const int bid = blockIdx.x;
    const int xcd = bid & 7, slot = bid >> 3;        // 624 slots per XCD
    const int grp = xcd * 104 + slot / 6;
    const int nx  = slot % 6;
    const int l   = grp >> 6;                        // layer 0..12
    const long m0 = (long)(grp & 63) * 128;
    const long n0 = (long)nx * 128;

    const int t = threadIdx.x, lane = t & 63, wave = t >> 6;

    const float* Ab = A + (size_t)l * aLS;
    const unsigned short* Bb = B + (size_t)l * bLS;
    const float* bias = biasBase + (size_t)l * biasLS;

    // A: dest row = wave*8 + (lane>>3), dest chunk = lane&7 (16B chunks of 128B row)
    //    source chunk = (lane&7) ^ (row&7)   [involution]
    const int arow = wave * 8 + (lane >> 3);
    const int achk = (lane & 7) ^ (lane >> 3);
    // B: dest row = wave*16 + (lane>>2), dest chunk = lane&3 (16B chunks of 64B row)
    //    source chunk = (lane&3) ^ ((row>>1)&3)
    const int brow = wave * 16 + (lane >> 2);
    const int bchk = (lane & 3) ^ ((lane >> 3) & 3);
    const int dA   = wave * 1024 + lane * 16;

    const int wm = (wave >> 1) * 64;
    const int wn = (wave & 1) * 64;
    const int lr = lane & 15;
    const int g4 = lane >> 4;
    const int kg = g4 * 8;
    const int swzB = ((lr >> 1) & 3) * 8;   // ushort units

    f32x4 acc[4][4];
#pragma unroll
    for (int i = 0; i < 4; i++)
#pragma unroll
        for (int j = 0; j < 4; j++) acc[i][j] = (f32x4){0.f, 0.f, 0.f, 0.f};

    auto STAGE = [&](int buf, int k0) {
        char* la = (char*)lsA[buf];
        char* lb = (char*)lsB[buf];
#pragma unroll
        for (int i = 0; i < 4; i++) {
            const char* src = (const char*)(Ab + (m0 + i * 32 + arow) * (size_t)K + k0) + achk * 16;
            gload16(src, la + i * 4096 + dA);
        }
#pragma unroll
        for (int i = 0; i < 2; i++) {
            const char* src = (const char*)(Bb + (n0 + i * 64 + brow) * (size_t)K + k0) + bchk * 16;
            gload16(src, lb + i * 4096 + dA);
        }
    };
    auto COMP = [&](int buf) {
        short8 af[4], bv[4];
        const float* pa = lsA[buf];
        const unsigned short* pb = lsB[buf];
#pragma unroll
        for (int mi = 0; mi < 4; mi++) {
            int row = wm + mi * 16 + lr;
            const char* base = (const char*)(pa + row * 32);
            float4 x0 = *(const float4*)(base + (((2 * g4 + 0) ^ (row & 7)) << 4));
            float4 x1 = *(const float4*)(base + (((2 * g4 + 1) ^ (row & 7)) << 4));
            union { short8 s; unsigned u[4]; } ua;
            ua.u[0] = cvtpk(x0.x, x0.y); ua.u[1] = cvtpk(x0.z, x0.w);
            ua.u[2] = cvtpk(x1.x, x1.y); ua.u[3] = cvtpk(x1.z, x1.w);
            af[mi] = ua.s;
        }
#pragma unroll
        for (int ni = 0; ni < 4; ni++)
            bv[ni] = *(const short8*)&pb[(wn + ni * 16 + lr) * 32 + (kg ^ swzB)];
#pragma unroll
        for (int mi = 0; mi < 4; mi++)
#pragma unroll
            for (int ni = 0; ni < 4; ni++)
                acc[mi][ni] = __builtin_amdgcn_mfma_f32_16x16x32_bf16(
                    af[mi], bv[ni], acc[mi][ni], 0, 0, 0);
    };

    STAGE(0, 0);
    __syncthreads();
    int cur = 0;
    const int nst = K >> 5;
    for (int ks = 1; ks < nst; ks++) {
        STAGE(cur ^ 1, ks * 32);
        COMP(cur);
        __syncthreads();
        cur ^= 1;
    }
    COMP(cur);

#pragma unroll
    for (int ni = 0; ni < 4; ni++) {
        long col = n0 + wn + ni * 16 + lr;
        float bvs = bias[col];
#pragma unroll
        for (int mi = 0; mi < 4; mi++) {
#pragma unroll
            for (int r = 0; r < 4; r++) {
                long grow = m0 + wm + mi * 16 + (lane >> 4) * 4 + r;
                size_t coff = (size_t)grow * cRowStride + (size_t)l * cLayerOff + col;
                C[coff] = f2bf(acc[mi][ni][r] + bvs);
            }
        }
    }
}

// ---------------------------------------------------------------------------
// GEMM2: C(f32) = A(bf16) * B(bf16)^T + bias.  Same scheme.
// grid = 384 (8 XCD x 8 groups x 6 n-blocks).
// ---------------------------------------------------------------------------
__global__ __launch_bounds__(256) void gemm_bf16_nt(
    const unsigned short* __restrict__ A, const unsigned short* __restrict__ B,
    const float* __restrict__ bias, float* __restrict__ C,
    int K, long cRowStride)
{
    __shared__ __align__(16) unsigned short lsA[2][4096];
    __shared__ __align__(16) unsigned short lsB[2][4096];

    const int bid = blockIdx.x;
    const int xcd = bid & 7, slot = bid >> 3;        // 48 slots per XCD
    const int grp = xcd * 8 + slot / 6;              // 0..63
    const int nx  = slot % 6;
    const long m0 = (long)grp * 128;
    const long n0 = (long)nx * 128;

    const int t = threadIdx.x, lane = t & 63, wave = t >> 6;

    const int brow = wave * 16 + (lane >> 2);
    const int bchk = (lane & 3) ^ ((lane >> 3) & 3);
    const int dA   = wave * 1024 + lane * 16;

    const int wm = (wave >> 1) * 64;
    const int wn = (wave & 1) * 64;
    const int lr = lane & 15;
    const int g4 = lane >> 4;
    const int kg = g4 * 8;
    const int swz = ((lr >> 1) & 3) * 8;

    f32x4 acc[4][4];
#pragma unroll
    for (int i = 0; i < 4; i++)
#pragma unroll
        for (int j = 0; j < 4; j++) acc[i][j] = (f32x4){0.f, 0.f, 0.f, 0.f};

    auto STAGE = [&](int buf, int k0) {
        char* la = (char*)lsA[buf];
        char* lb = (char*)lsB[buf];
#pragma unroll
        for (int i = 0; i < 2; i++) {
            const char* sa = (const char*)(A + (m0 + i * 64 + brow) * (size_t)K + k0) + bchk * 16;
            const char* sb = (const char*)(B + (n0 + i * 64 + brow) * (size_t)K + k0) + bchk * 16;
            gload16(sa, la + i * 4096 + dA);
            gload16(sb, lb + i * 4096 + dA);
        }
    };
    auto COMP = [&](int buf) {
        short8 af[4], bv[4];
        const unsigned short* pa = lsA[buf];
        const unsigned short* pb = lsB[buf];
#pragma unroll
        for (int mi = 0; mi < 4; mi++)
            af[mi] = *(const short8*)&pa[(wm + mi * 16 + lr) * 32 + (kg ^ swz)];
#pragma unroll
        for (int ni = 0; ni < 4; ni++)
            bv[ni] = *(const short8*)&pb[(wn + ni * 16 + lr) * 32 + (kg ^ swz)];
#pragma unroll
        for (int mi = 0; mi < 4; mi++)
#pragma unroll
            for (int ni = 0; ni < 4; ni++)
                acc[mi][ni] = __builtin_amdgcn_mfma_f32_16x16x32_bf16(
                    af[mi], bv[ni], acc[mi][ni], 0, 0, 0);
    };

    STAGE(0, 0);
    __syncthreads();
    int cur = 0;
    const int nst = K >> 5;
    for (int ks = 1; ks < nst; ks++) {
        STAGE(cur ^ 1, ks * 32);
        COMP(cur);
        __syncthreads();
        cur ^= 1;
    }
    COMP(cur);

#pragma unroll
    for (int ni = 0; ni < 4; ni++) {
        long col = n0 + wn + ni * 16 + lr;
        float bvs = bias[col];
#pragma unroll
        for (int mi = 0; mi < 4; mi++) {
#pragma unroll
            for (int r = 0; r < 4; r++) {
                long grow = m0 + wm + mi * 16 + (lane >> 4) * 4 + r;
                C[(size_t)grow * cRowStride + col] = acc[mi][ni][r] + bvs;
            }
        }
    }
}

// ---------------------------------------------------------------------------
// Fold kvln gamma into k_w; compute s_k = sum(kw*g), c_k = kw.b + k_bias.
// ---------------------------------------------------------------------------
__global__ __launch_bounds__(256) void wtrans(
    const float* __restrict__ kw, const float* __restrict__ kvg,
    const float* __restrict__ kvb, const float* __restrict__ kbias,
    float* __restrict__ kwp, float* __restrict__ skv, float* __restrict__ ckv)
{
    __shared__ float red[8];
    const int q = blockIdx.x, t = threadIdx.x;
    const int lane = t & 63, wave = t >> 6;
    float s = 0.f, c = 0.f;
    for (int v = t; v < 768; v += 256) {
        float w = kw[q * 768 + v];
        float wp = w * kvg[v];
        kwp[q * 768 + v] = wp;
        s += wp;
        c += w * kvb[v];
    }
#pragma unroll
    for (int off = 1; off < 64; off <<= 1) {
        s += __shfl_xor(s, off);
        c += __shfl_xor(c, off);
    }
    if (lane == 0) { red[wave] = s; red[4 + wave] = c; }
    __syncthreads();
    if (t == 0) {
        skv[q] = red[0] + red[1] + red[2] + red[3];
        ckv[q] = red[4] + red[5] + red[6] + red[7] + kbias[q];
    }
}

// ---------------------------------------------------------------------------
// LayerNorm rows of 768 (fp32 src) -> bf16.  Q side only.
// ---------------------------------------------------------------------------
__global__ __launch_bounds__(256) void ln_rows_f32(
    const float* __restrict__ src, unsigned short* __restrict__ dst,
    const float* __restrict__ gam, const float* __restrict__ bet)
{
    const int lane = threadIdx.x & 63;
    const int wave = threadIdx.x >> 6;
    const size_t row = (size_t)blockIdx.x * 4 + wave;

    float x[3][4];
    float s = 0.f, sq = 0.f;
#pragma unroll
    for (int i = 0; i < 3; i++) {
        int v = i * 256 + lane * 4;
        float4 f = *(const float4*)(src + row * 768 + v);
        x[i][0] = f.x; x[i][1] = f.y; x[i][2] = f.z; x[i][3] = f.w;
#pragma unroll
        for (int e = 0; e < 4; e++) { s += x[i][e]; sq += x[i][e] * x[i][e]; }
    }
#pragma unroll
    for (int off = 1; off < 64; off <<= 1) {
        s  += __shfl_xor(s, off);
        sq += __shfl_xor(sq, off);
    }
    float mean = s * (1.f / 768.f);
    float var  = sq * (1.f / 768.f) - mean * mean;
    float rs   = rsqrtf(var + 1e-5f);
#pragma unroll
    for (int i = 0; i < 3; i++) {
        int v = i * 256 + lane * 4;
        float4 gg = *(const float4*)(gam + v);
        float4 bb = *(const float4*)(bet + v);
        ushort4 o;
        o.x = f2bf((x[i][0] - mean) * rs * gg.x + bb.x);
        o.y = f2bf((x[i][1] - mean) * rs * gg.y + bb.y);
        o.z = f2bf((x[i][2] - mean) * rs * gg.z + bb.z);
        o.w = f2bf((x[i][3] - mean) * rs * gg.w + bb.w);
        *(ushort4*)(dst + row * 768 + v) = o;
    }
}

// ---------------------------------------------------------------------------
// proj32: out[M][32] = A[M][768](bf16) @ W[32][768](f32)^T + bias (plain).
// ---------------------------------------------------------------------------
__global__ __launch_bounds__(256) void proj32(
    const unsigned short* __restrict__ A, const float* __restrict__ W,
    const float* __restrict__ bias, unsigned short* __restrict__ out)
{
    __shared__ __align__(16) unsigned short lsW[32 * 776];
    __shared__ __align__(16) unsigned short lsA[128 * 40];
    const int t = threadIdx.x;

#pragma unroll
    for (int i = 0; i < 24; i++) {
        int fi = t + i * 256;
        int row = fi / 192;
        int c4  = fi % 192;
        float4 f = *(const float4*)(W + row * 768 + c4 * 4);
        ushort4 u;
        u.x = f2bf(f.x); u.y = f2bf(f.y); u.z = f2bf(f.z); u.w = f2bf(f.w);
        *(ushort4*)&lsW[row * 776 + c4 * 4] = u;
    }

    const size_t m0 = (size_t)blockIdx.x * 128;
    const int lane = t & 63, wave = t >> 6;
    const int wm = wave * 32;
    const int lr = lane & 15, kg = (lane >> 4) * 8;
    const int row_s = t >> 3, c4s = t & 7;

    f32x4 acc[2][2];
#pragma unroll
    for (int i = 0; i < 2; i++)
#pragma unroll
        for (int j = 0; j < 2; j++) acc[i][j] = (f32x4){0.f, 0.f, 0.f, 0.f};

    __syncthreads();

    for (int k0 = 0; k0 < 768; k0 += 32) {
#pragma unroll
        for (int i = 0; i < 4; i++) {
            int row = row_s + 32 * i;
            ushort4 v = *(const ushort4*)(A + (m0 + row) * 768 + k0 + c4s * 4);
            *(ushort4*)&lsA[row * 40 + c4s * 4] = v;
        }
        __syncthreads();
        short8 af[2], bw[2];
#pragma unroll
        for (int mi = 0; mi < 2; mi++)
            af[mi] = *(const short8*)&lsA[(wm + mi * 16 + lr) * 40 + kg];
#pragma unroll
        for (int ni = 0; ni < 2; ni++)
            bw[ni] = *(const short8*)&lsW[(ni * 16 + lr) * 776 + k0 + kg];
#pragma unroll
        for (int mi = 0; mi < 2; mi++)
#pragma unroll
            for (int ni = 0; ni < 2; ni++)
                acc[mi][ni] = __builtin_amdgcn_mfma_f32_16x16x32_bf16(
                    af[mi], bw[ni], acc[mi][ni], 0, 0, 0);
        __syncthreads();
    }

#pragma unroll
    for (int ni = 0; ni < 2; ni++) {
        int col = ni * 16 + lr;
        float bv = bias[col];
#pragma unroll
        for (int mi = 0; mi < 2; mi++) {
#pragma unroll
            for (int r = 0; r < 4; r++) {
                size_t grow = m0 + wm + mi * 16 + (lane >> 4) * 4 + r;
                out[grow * 32 + col] = f2bf(acc[mi][ni][r] + bv);
            }
        }
    }
}

// ---------------------------------------------------------------------------
// proj32k_stats: k = rs*(dot(x_raw, kwp) - mean*s_k) + c_k, with row stats
// computed in the K-loop.
// ---------------------------------------------------------------------------
__global__ __launch_bounds__(256) void proj32k_stats(
    const unsigned short* __restrict__ A, const float* __restrict__ W,
    const float* __restrict__ skv, const float* __restrict__ ckv,
    unsigned short* __restrict__ out, float2* __restrict__ st)
{
    __shared__ __align__(16) unsigned short lsW[32 * 776];
    __shared__ __align__(16) unsigned short lsA[128 * 40];
    __shared__ float2 lstat[128];
    const int t = threadIdx.x;

#pragma unroll
    for (int i = 0; i < 24; i++) {
        int fi = t + i * 256;
        int row = fi / 192;
        int c4  = fi % 192;
        float4 f = *(const float4*)(W + row * 768 + c4 * 4);
        ushort4 u;
        u.x = f2bf(f.x); u.y = f2bf(f.y); u.z = f2bf(f.z); u.w = f2bf(f.w);
        *(ushort4*)&lsW[row * 776 + c4 * 4] = u;
    }

    const size_t m0 = (size_t)blockIdx.x * 128;
    const int lane = t & 63, wave = t >> 6;
    const int wm = wave * 32;
    const int lr = lane & 15, kg = (lane >> 4) * 8;
    const int row_s = t >> 3, c4s = t & 7;

    f32x4 acc[2][2];
#pragma unroll
    for (int i = 0; i < 2; i++)
#pragma unroll
        for (int j = 0; j < 2; j++) acc[i][j] = (f32x4){0.f, 0.f, 0.f, 0.f};

    float s_[4] = {0.f, 0.f, 0.f, 0.f}, sq_[4] = {0.f, 0.f, 0.f, 0.f};

    __syncthreads();

    for (int k0 = 0; k0 < 768; k0 += 32) {
#pragma unroll
        for (int i = 0; i < 4; i++) {
            int row = row_s + 32 * i;
            ushort4 v = *(const ushort4*)(A + (m0 + row) * 768 + k0 + c4s * 4);
            *(ushort4*)&lsA[row * 40 + c4s * 4] = v;
            float x0 = bf2f(v.x), x1 = bf2f(v.y), x2 = bf2f(v.z), x3 = bf2f(v.w);
            s_[i]  += x0 + x1 + x2 + x3;
            sq_[i] += x0 * x0 + x1 * x1 + x2 * x2 + x3 * x3;
        }
        __syncthreads();
        short8 af[2], bw[2];
#pragma unroll
        for (int mi = 0; mi < 2; mi++)
            af[mi] = *(const short8*)&lsA[(wm + mi * 16 + lr) * 40 + kg];
#pragma unroll
        for (int ni = 0; ni < 2; ni++)
            bw[ni] = *(const short8*)&lsW[(ni * 16 + lr) * 776 + k0 + kg];
#pragma unroll
        for (int mi = 0; mi < 2; mi++)
#pragma unroll
            for (int ni = 0; ni < 2; ni++)
                acc[mi][ni] = __builtin_amdgcn_mfma_f32_16x16x32_bf16(
                    af[mi], bw[ni], acc[mi][ni], 0, 0, 0);
        __syncthreads();
    }

#pragma unroll
    for (int i = 0; i < 4; i++) {
#pragma unroll
        for (int off = 1; off < 8; off <<= 1) {
            s_[i]  += __shfl_xor(s_[i], off);
            sq_[i] += __shfl_xor(sq_[i], off);
        }
    }
    if (c4s == 0) {
#pragma unroll
        for (int i = 0; i < 4; i++) {
            int row = row_s + 32 * i;
            float mean = s_[i] * (1.f / 768.f);
            float var  = sq_[i] * (1.f / 768.f) - mean * mean;
            float2 sv = make_float2(mean, rsqrtf(var + 1e-5f));
            lstat[row] = sv;
            st[m0 + row] = sv;
        }
    }
    __syncthreads();

#pragma unroll
    for (int ni = 0; ni < 2; ni++) {
        int col = ni * 16 + lr;
        float sk = skv[col], ck = ckv[col];
#pragma unroll
        for (int mi = 0; mi < 2; mi++) {
#pragma unroll
            for (int r = 0; r < 4; r++) {
                int lrow = wm + mi * 16 + (lane >> 4) * 4 + r;
                float2 s2 = lstat[lrow];
                out[(m0 + lrow) * 32 + col] =
                    f2bf(s2.y * (acc[mi][ni][r] - s2.x * sk) + ck);
            }
        }
    }
}

// ---------------------------------------------------------------------------
// Attention on RAW aligned values with LN folded in.  One wave per token.
// ---------------------------------------------------------------------------
__global__ __launch_bounds__(256) void attn2(
    const unsigned short* __restrict__ qb, const unsigned short* __restrict__ kb,
    const unsigned short* __restrict__ kv, const float2* __restrict__ st,
    const float* __restrict__ gv, const float* __restrict__ bvv,
    unsigned short* __restrict__ oh)
{
    __shared__ float lat[4][4][13];
    __shared__ float latc[4][4];
    const int t = threadIdx.x, lane = t & 63, wave = t >> 6;
    const size_t m = (size_t)blockIdx.x * 4 + wave;

    if (lane < 32) {
        int j = lane;
        float qv = bf2f(qb[m * 32 + j]);
        float p[13];
#pragma unroll
        for (int l = 0; l < 13; l++)
            p[l] = qv * bf2f(kb[(m * 13 + l) * 32 + j]);
#pragma unroll
        for (int off = 1; off < 8; off <<= 1)
#pragma unroll
            for (int l = 0; l < 13; l++) p[l] += __shfl_xor(p[l], off);

        const float sc = 0.17677669529663687f; // 1 / (sqrt(8) * 2)
        float mx = -1e30f;
#pragma unroll
        for (int l = 0; l < 13; l++) { p[l] *= sc; mx = fmaxf(mx, p[l]); }
        float se = 0.f;
#pragma unroll
        for (int l = 0; l < 13; l++) { p[l] = __expf(p[l] - mx); se += p[l]; }
        float inv = 1.f / se;
        if ((j & 7) == 0) {
            int h = j >> 3;
            float corr = 0.f;
#pragma unroll
            for (int l = 0; l < 13; l++) {
                float2 s_ = st[m * 13 + l];
                float wl = p[l] * inv * s_.y;
                lat[wave][h][l] = wl;
                corr += wl * s_.x;
            }
            latc[wave][h] = corr;
        }
    }
    __syncthreads();

    f32x4 g4v[3], b4[3];
#pragma unroll
    for (int i = 0; i < 3; i++) {
        g4v[i] = *(const f32x4*)(gv + i * 256 + lane * 4);
        b4[i] = *(const f32x4*)(bvv + i * 256 + lane * 4);
    }

    float acc[4][3][4];
#pragma unroll
    for (int h = 0; h < 4; h++)
#pragma unroll
        for (int i = 0; i < 3; i++)
#pragma unroll
            for (int e = 0; e < 4; e++) acc[h][i][e] = 0.f;

    for (int l = 0; l < 13; l++) {
        float al[4];
#pragma unroll
        for (int h = 0; h < 4; h++) al[h] = lat[wave][h][l];
#pragma unroll
        for (int i = 0; i < 3; i++) {
            ushort4 u = *(const ushort4*)(kv + (m * 13 + l) * 768 + i * 256 + lane * 4);
            float xv[4] = {bf2f(u.x), bf2f(u.y), bf2f(u.z), bf2f(u.w)};
#pragma unroll
            for (int h = 0; h < 4; h++)
#pragma unroll
                for (int e = 0; e < 4; e++) acc[h][i][e] += al[h] * xv[e];
        }
    }
#pragma unroll
    for (int h = 0; h < 4; h++) {
        float ch = latc[wave][h];
#pragma unroll
        for (int i = 0; i < 3; i++) {
            ushort4 o;
            o.x = f2bf(g4v[i][0] * (acc[h][i][0] - ch) + b4[i][0]);
            o.y = f2bf(g4v[i][1] * (acc[h][i][1] - ch) + b4[i][1]);
            o.z = f2bf(g4v[i][2] * (acc[h][i][2] - ch) + b4[i][2]);
            o.w = f2bf(g4v[i][3] * (acc[h][i][3] - ch) + b4[i][3]);
            *(ushort4*)(oh + m * 3072 + h * 768 + i * 256 + lane * 4) = o;
        }
    }
}

// ---------------------------------------------------------------------------
extern "C" void kernel_launch(void* const* d_in, const int* in_sizes, int n_in,
                              void* d_out, int out_size, void* d_ws, size_t ws_size,
                              hipStream_t stream) {
    const float* base  = (const float*)d_in[0];
    const float* reps  = (const float*)d_in[1];
    const float* aw    = (const float*)d_in[2];
    const float* ab    = (const float*)d_in[3];
    const float* qg    = (const float*)d_in[4];
    const float* qbeta = (const float*)d_in[5];
    const float* kvg   = (const float*)d_in[6];
    const float* kvb   = (const float*)d_in[7];
    const float* qw    = (const float*)d_in[8];
    const float* qbias = (const float*)d_in[9];
    const float* kw    = (const float*)d_in[10];
    const float* kbias = (const float*)d_in[11];
    const float* ow    = (const float*)d_in[12];
    const float* obias = (const float*)d_in[13];
    float* out = (float*)d_out;

    float2* stats = (float2*)d_ws;                              // [MROWS]
    float* kwp = (float*)(stats + MROWS);                       // [32][768]
    float* skv = kwp + 32 * 768;                                // [32]
    float* ckv = skv + 32;                                      // [32]
    unsigned short* aligned = (unsigned short*)(ckv + 32);      // [MROWS][768]
    unsigned short* UNION = aligned + (size_t)MROWS * 768;      // awb -> Qn -> oh
    unsigned short* kbuf = UNION + (size_t)MTOK * 3072;         // [MROWS][32]
    unsigned short* qbuf = kbuf + (size_t)MROWS * 32;           // [MTOK][32]
    unsigned short* owb  = qbuf + (size_t)MTOK * 32;            // [768][3072]

    unsigned short* awb = UNION;

    // 0. weight conversions + LN folding precompute
    {
        long n = (long)NL * 768 * 768;
        conv_f32_bf16<<<(int)(n / 8 / 256), 256, 0, stream>>>(aw, awb, n);
        long n2 = (long)768 * 3072;
        conv_f32_bf16<<<(int)(n2 / 8 / 256), 256, 0, stream>>>(ow, owb, n2);
        wtrans<<<32, 256, 0, stream>>>(kw, kvg, kvb, kbias, kwp, skv, ckv);
    }

    // 1. aligner GEMM (XCD-grouped, coalesced+swizzled staging)
    gemm_f32a<<<4992, 256, 0, stream>>>(
        reps, awb, ab, aligned,
        768, (long)MTOK * 768, (long)768 * 768, 768,
        768L, (long)NL * 768);

    // 2. k projection + fused row stats
    proj32k_stats<<<MROWS / 128, 256, 0, stream>>>(
        aligned, kwp, skv, ckv, kbuf, stats);

    // 3. q side: LN(base) -> Qn, then proj32 (awb dead, reuse UNION)
    unsigned short* Qn = UNION;
    ln_rows_f32<<<MTOK / 4, 256, 0, stream>>>(base, Qn, qg, qbeta);
    proj32<<<MTOK / 128, 256, 0, stream>>>(Qn, qw, qbias, qbuf);

    // 4. attention on raw aligned (Qn dead, reuse UNION for oh)
    unsigned short* oh = UNION;
    attn2<<<MTOK / 4, 256, 0, stream>>>(qbuf, kbuf, aligned, stats, kvg, kvb, oh);

    // 5. out = out_heads @ out_w^T + out_b
    gemm_bf16_nt<<<384, 256, 0, stream>>>(oh, owb, obias, out, 3072, 768L);
}